// Round 1
// 327.710 us; speedup vs baseline: 1.0614x; 1.0614x over previous
//
#include <hip/hip_runtime.h>

#define DI __device__ __forceinline__

constexpr int Bc = 4, Tc = 4096, Ic = 1024, Ec = 16, Kc = 512, Jc = 1024;

typedef __attribute__((ext_vector_type(8))) short short8;
typedef __attribute__((ext_vector_type(4))) float floatx4;

// pack two fp32 -> two bf16 (round-half-up): low16 = bf16(a), high16 = bf16(b)
DI unsigned pack2_bf16(float a, float b) {
  union { float f; unsigned u; } ua, ub;
  ua.f = a; ub.f = b;
  const unsigned x = ua.u + 0x8000u;
  const unsigned y = ub.u + 0x8000u;
#if __has_builtin(__builtin_amdgcn_perm)
  return __builtin_amdgcn_perm(y, x, 0x07060302u);
#else
  return (x >> 16) | (y & 0xFFFF0000u);
#endif
}

DI void async_load16(const void* g, void* lds) {
  __builtin_amdgcn_global_load_lds((const __attribute__((address_space(1))) void*)g,
                                   (__attribute__((address_space(3))) void*)lds,
                                   16, 0, 0);
}

// ---------------------------------------------------------------------------
// Fused prep (UNCHANGED). Even blocks: gather+cast X into Xg[tile][kk][128][32].
// Odd blocks: transpose+cast W into Wt[(e*8+jt)*32+kk][128n][32i].
__global__ __launch_bounds__(256) void prep(const float* __restrict__ X,
                                            const int* __restrict__ ind,
                                            const float* __restrict__ W,
                                            unsigned short* __restrict__ Xg,
                                            unsigned short* __restrict__ Wt) {
  __shared__ __align__(16) char smem[32 * 260 * 2];
  const int bid = blockIdx.x >> 1;
  const int t = threadIdx.x;

  if ((blockIdx.x & 1) == 0) {
    unsigned short* Ls = (unsigned short*)smem;
    const int g = t >> 5, kk = t & 31;
    const int R = bid * 8 + g;
    const int b = R >> 13;
    const int xr = ind[R];
    const float* src = X + ((size_t)(b * Tc + xr)) * Ic + kk * 32;
    unsigned u[16];
#pragma unroll
    for (int q = 0; q < 8; ++q) {
      const float4 v = *(const float4*)(src + q * 4);
      u[2 * q]     = pack2_bf16(v.x, v.y);
      u[2 * q + 1] = pack2_bf16(v.z, v.w);
    }
    unsigned short* lp = &Ls[kk * 260 + g * 32];
#pragma unroll
    for (int q = 0; q < 4; ++q) *(uint4*)(lp + q * 8) = *(uint4*)&u[4 * q];
    __syncthreads();
    const int kk2 = t >> 3, rw = t & 7;
    const int tt = bid >> 4;
    const int rl0 = (bid & 15) * 8;
    unsigned short* dst = Xg + ((size_t)(tt * 32 + kk2) * 128 + rl0 + rw) * 32;
    const unsigned short* lr = &Ls[kk2 * 260 + rw * 32];
#pragma unroll
    for (int q = 0; q < 4; ++q) *(uint4*)(dst + q * 8) = *(const uint4*)(lr + q * 8);
  } else {
    float (*tile)[129] = (float(*)[129])smem;
    const int kk = bid & 31;
    const int jt = (bid >> 5) & 7;
    const int e  = bid >> 8;
    const float* Wp = W + ((size_t)(e * Ic + kk * 32)) * Jc + jt * 128;
#pragma unroll
    for (int p = 0; p < 4; ++p) {
      const int il = p * 8 + (t >> 5);
      const int c4 = (t & 31) * 4;
      const float4 v = *(const float4*)(Wp + (size_t)il * Jc + c4);
      tile[il][c4 + 0] = v.x; tile[il][c4 + 1] = v.y;
      tile[il][c4 + 2] = v.z; tile[il][c4 + 3] = v.w;
    }
    __syncthreads();
    unsigned short* out = Wt + ((size_t)((e * 8 + jt) * 32 + kk)) * 4096;
#pragma unroll
    for (int h = 0; h < 2; ++h) {
      const int n   = h * 64 + (t >> 2);
      const int il0 = (t & 3) * 8;
      unsigned u[4];
#pragma unroll
      for (int q = 0; q < 4; ++q)
        u[q] = pack2_bf16(tile[il0 + 2 * q][n], tile[il0 + 2 * q + 1][n]);
      *(uint4*)(out + (size_t)(h * 256 + t) * 8) = *(uint4*)u;
    }
  }
}

// ---------------------------------------------------------------------------
// 256x256 tile, BK=32, 8 waves (2Mx4N, per-wave 128x64 out), 4-deep LDS ring,
// counted vmcnt(8) pipeline (never drains to 0 in steady state), 1 barrier/tile.
// LDS chunk layout [128r][4 pos][8 el]; pos stored = orig ^ ((row>>1)&3),
// applied on the global SOURCE address (dest stays linear for global_load_lds)
// and on the ds_read side => 2-way (free) bank aliasing instead of 4-way.
__global__ __launch_bounds__(512, 2) void moe_gemm(const unsigned short* __restrict__ Xg,
                                                   const unsigned short* __restrict__ Wt,
                                                   float* __restrict__ Y) {
  __shared__ __align__(16) unsigned short As[4 * 8192];   // 4 bufs x 16 KB (A: 256r x 32k)
  __shared__ __align__(16) unsigned short Bs[4 * 8192];   // 4 bufs x 16 KB (B: 256n x 32k)

  // bijective XCD-chunked mapping: each XCD gets 64 contiguous logical blocks
  // (= 2 experts); within an expert: nt fastest so A-panel siblings are adjacent.
  const int bid   = blockIdx.x;                 // 512 blocks
  const int lg    = (bid & 7) * 64 + (bid >> 3);
  const int e     = lg >> 5;
  const int inner = lg & 31;
  const int b     = inner >> 3;
  const int mt    = (inner >> 2) & 1;           // which 256 rows of K=512
  const int nt    = inner & 3;                  // which 256 cols of J=1024

  const int t = threadIdx.x;
  const int w = t >> 6;                         // wave 0..7
  const int l = t & 63;
  const int lrow = l & 15;
  const int q    = l >> 4;

  const int tt0 = b * 64 + e * 4 + mt * 2;      // first 128-row Xg tile
  const int jg0 = e * 8 + nt * 2;               // first 128-col Wt group

  // staging: thread t owns LDS bytes [t*16, t*16+16) of an 8 KB chunk
  // -> row sr = t>>2, pos sc = t&3; source pos pre-swizzled.
  const int sr = t >> 2, sc = t & 3;
  const size_t lsrc = (size_t)sr * 32 + ((sc ^ ((sr >> 1) & 3)) << 3);

  const unsigned short* aC = Xg + (size_t)tt0 * 32 * 4096 + lsrc;
  const unsigned short* bC = Wt + (size_t)jg0 * 32 * 4096 + lsrc;
  unsigned short* aL = As + w * 512;            // wave-uniform dest; HW adds lane*16B
  unsigned short* bL = Bs + w * 512;

  auto stage = [&](int k3) {                    // 4 loads/wave/tile
    const int bu = (k3 & 3) * 8192;
#pragma unroll
    for (int p = 0; p < 2; ++p) {
      async_load16(aC + ((size_t)(p * 32 + k3)) * 4096, aL + bu + p * 4096);
      async_load16(bC + ((size_t)(p * 32 + k3)) * 4096, bL + bu + p * 4096);
    }
  };

  floatx4 acc[8][4];
#pragma unroll
  for (int tm = 0; tm < 8; ++tm)
#pragma unroll
    for (int tn = 0; tn < 4; ++tn) acc[tm][tn] = (floatx4){0.f, 0.f, 0.f, 0.f};

  // ds_read bases: read swizzled pos = q ^ ((row>>1)&3); row-multiples of 16
  // leave the swizzle = (lrow>>1)&3 for every fragment.
  const int pos = (q ^ ((lrow >> 1) & 3)) << 3;
  const unsigned short* Ard = As + ((w >> 2) << 12) + lrow * 32 + pos;
  const unsigned short* Brd = Bs + (((w >> 1) & 1) << 12) + ((w & 1) * 64 + lrow) * 32 + pos;

  stage(0); stage(1); stage(2);                 // prime 3 tiles (12 loads in flight)

  auto compute = [&](int kt) {
    const int bu = (kt & 3) * 8192;
    short8 bf[4];
#pragma unroll
    for (int tn = 0; tn < 4; ++tn) bf[tn] = *(const short8*)(Brd + bu + tn * 512);
    __builtin_amdgcn_s_setprio(1);
#pragma unroll
    for (int h = 0; h < 2; ++h) {
      short8 af[4];
#pragma unroll
      for (int i2 = 0; i2 < 4; ++i2)
        af[i2] = *(const short8*)(Ard + bu + (h * 4 + i2) * 512);
#pragma unroll
      for (int i2 = 0; i2 < 4; ++i2)
#pragma unroll
        for (int tn = 0; tn < 4; ++tn)
          acc[h * 4 + i2][tn] =
              __builtin_amdgcn_mfma_f32_16x16x32_bf16(af[i2], bf[tn], acc[h * 4 + i2][tn], 0, 0, 0);
    }
    __builtin_amdgcn_s_setprio(0);
  };

#define WAITVM(n) asm volatile("s_waitcnt vmcnt(" #n ")" ::: "memory")
#define CFENCE    asm volatile("" ::: "memory")

  // steady state: tiles kt,kt+1,kt+2 in flight (12 loads); vmcnt(8) = tile kt done.
  // barrier => ALL waves' loads for kt landed AND all waves finished reading kt-1,
  // so issuing kt+3 into buf[(kt+3)&3] == buf[(kt-1)&3] is race-free.
#pragma unroll 4
  for (int kt = 0; kt < 28; ++kt) {
    WAITVM(8);
    __builtin_amdgcn_s_barrier();
    CFENCE;
    stage(kt + 3);
    compute(kt);
  }
  WAITVM(8); __builtin_amdgcn_s_barrier(); CFENCE; stage(31); compute(28);
  WAITVM(8); __builtin_amdgcn_s_barrier(); CFENCE; compute(29);
  WAITVM(4); __builtin_amdgcn_s_barrier(); CFENCE; compute(30);
  WAITVM(0); __builtin_amdgcn_s_barrier(); CFENCE; compute(31);

  // epilogue: C/D layout col = lane&15, row = quad*4 + reg
  float* Yp = Y + (((size_t)(b * Ec + e) * Kc + (size_t)mt * 256) * Jc) + nt * 256;
  const int wmRow = (w >> 2) * 128;
  const int wnCol = (w & 3) * 64;
#pragma unroll
  for (int tm = 0; tm < 8; ++tm) {
#pragma unroll
    for (int tn = 0; tn < 4; ++tn) {
#pragma unroll
      for (int r = 0; r < 4; ++r) {
        const int row = wmRow + tm * 16 + q * 4 + r;
        const int col = wnCol + tn * 16 + lrow;
        Yp[(size_t)row * Jc + col] = acc[tm][tn][r];
      }
    }
  }
}

extern "C" void kernel_launch(void* const* d_in, const int* in_sizes, int n_in,
                              void* d_out, int out_size, void* d_ws, size_t ws_size,
                              hipStream_t stream) {
  const float* X = (const float*)d_in[0];
  const int* ind = (const int*)d_in[1];
  const float* W = (const float*)d_in[2];
  float* Y = (float*)d_out;

  unsigned short* Xg = (unsigned short*)d_ws;                              // 64 MiB
  unsigned short* Wt = (unsigned short*)d_ws + (size_t)Bc * Ec * Kc * Ic;  // 32 MiB

  hipLaunchKernelGGL(prep, dim3(8192), dim3(256), 0, stream, X, ind, W, Xg, Wt);
  hipLaunchKernelGGL(moe_gemm, dim3(512), dim3(512), 0, stream, Xg, Wt, Y);
}